// Round 1
// baseline (177.606 us; speedup 1.0000x reference)
//
#include <hip/hip_runtime.h>

// Hungarian matcher: B=32 batches, Q=300 preds, T=50 truths.
// One 64-lane wave per batch. Column state (300 cols) distributed across
// lanes in registers, 5 slots/lane (col j owned by lane j&63, slot j>>6).
// LSA arithmetic in double, matching numpy op order exactly.

#define NQ 300
#define NT 50
#define NSLOT 5 // ceil(300/64)

__global__ __launch_bounds__(64) void hungarian_kernel(
    const float* __restrict__ pred, const float* __restrict__ truth,
    int* __restrict__ out)
{
#pragma clang fp contract(off)
    const int b = blockIdx.x;
    const int lane = threadIdx.x;

    __shared__ float cost[NT * NQ];     // [t][q], t = LSA row, q = LSA col
    __shared__ double u[NT];
    __shared__ double sh_short[NQ];     // shortest dump for u-update gather
    __shared__ int col4row[NT];

    const float* pb = pred + b * NQ * 4;
    const float* tb = truth + b * NT * 4;

    // ---- cost matrix: C[t][q] = 5*L1 + 2*(-giou), reference op order ----
    for (int idx = lane; idx < NT * NQ; idx += 64) {
        int t = idx / NQ;
        int q = idx - t * NQ;
        float pcx = pb[q*4+0], pcy = pb[q*4+1], pw = pb[q*4+2], ph = pb[q*4+3];
        float tcx = tb[t*4+0], tcy = tb[t*4+1], tw = tb[t*4+2], th = tb[t*4+3];
        // sum(|.|) in numpy left-to-right order
        float cb = ((fabsf(pcx-tcx) + fabsf(pcy-tcy)) + fabsf(pw-tw)) + fabsf(ph-th);
        float px1 = pcx - 0.5f*pw, py1 = pcy - 0.5f*ph;
        float px2 = pcx + 0.5f*pw, py2 = pcy + 0.5f*ph;
        float tx1 = tcx - 0.5f*tw, ty1 = tcy - 0.5f*th;
        float tx2 = tcx + 0.5f*tw, ty2 = tcy + 0.5f*th;
        float area1 = (px2-px1)*(py2-py1);
        float area2 = (tx2-tx1)*(ty2-ty1);
        float ltx = fmaxf(px1, tx1), lty = fmaxf(py1, ty1);
        float rbx = fminf(px2, tx2), rby = fminf(py2, ty2);
        float w = fmaxf(rbx-ltx, 0.f), h = fmaxf(rby-lty, 0.f);
        float inter = w*h;
        float uni = (area1 + area2) - inter;
        float iou = inter/uni;
        float ex1 = fminf(px1,tx1), ey1 = fminf(py1,ty1);
        float ex2 = fmaxf(px2,tx2), ey2 = fmaxf(py2,ty2);
        float ew = fmaxf(ex2-ex1, 0.f), eh = fmaxf(ey2-ey1, 0.f);
        float ae = ew*eh;
        float g = iou - (ae - uni)/ae;
        cost[t*NQ + q] = 5.0f*cb + 2.0f*(-g);
    }
    if (lane < NT) { u[lane] = 0.0; col4row[lane] = -1; }

    // per-lane distributed column state
    double v_reg[NSLOT], short_reg[NSLOT];
    int path_reg[NSLOT], r4c_reg[NSLOT];
    for (int k = 0; k < NSLOT; ++k) { v_reg[k] = 0.0; r4c_reg[k] = -1; }
    __syncthreads();

    for (int cur = 0; cur < NT; ++cur) {
        unsigned oncol = 0;                 // per-lane: bit k -> col lane+64k marked
        unsigned long long onrow = 0;       // wave-uniform
        for (int k = 0; k < NSLOT; ++k) { short_reg[k] = __builtin_inf(); path_reg[k] = -1; }
        double min_val = 0.0;
        int i = cur, sink = -1;

        while (sink < 0) {
            onrow |= 1ull << i;
            double u_i = u[i];              // broadcast LDS read
            const float* crow = cost + i * NQ;
            double bv = __builtin_inf();
            int bj = 0x7fffffff;
            for (int k = 0; k < NSLOT; ++k) {
                int j = lane + (k << 6);
                if (j < NQ && !((oncol >> k) & 1u)) {
                    // numpy order: ((min_val + cost) - u[i]) - v[j]
                    double d = ((min_val + (double)crow[j]) - u_i) - v_reg[k];
                    if (d < short_reg[k]) { short_reg[k] = d; path_reg[k] = i; }
                    if (short_reg[k] < bv) { bv = short_reg[k]; bj = j; }
                }
            }
            // wave argmin; tie -> smaller column index (numpy first-occurrence)
            for (int off = 32; off >= 1; off >>= 1) {
                double ov = __shfl_xor(bv, off);
                int oj = __shfl_xor(bj, off);
                if (ov < bv || (ov == bv && oj < bj)) { bv = ov; bj = oj; }
            }
            int j = bj;
            min_val = bv;
            int kj = j >> 6, lj = j & 63;
            if (lane == lj) oncol |= 1u << kj;
            int r = __shfl(r4c_reg[kj], lj);   // row4col[j]
            if (r < 0) sink = j; else i = r;
        }

        // dump shortest for the u-update gather
        for (int k = 0; k < NSLOT; ++k) {
            int j = lane + (k << 6);
            if (j < NQ) sh_short[j] = short_reg[k];
        }
        __syncthreads();

        // u updates (before augmentation walk, as in reference)
        if (lane < NT) {
            if (lane == cur) {
                u[lane] = u[lane] + min_val;
            } else if ((onrow >> lane) & 1ull) {
                int c = col4row[lane];
                u[lane] = u[lane] + (min_val - sh_short[c]);
            }
        }
        // v updates: lane-local columns marked on_col
        for (int k = 0; k < NSLOT; ++k) {
            int j = lane + (k << 6);
            if (j < NQ && ((oncol >> k) & 1u))
                v_reg[k] = v_reg[k] - (min_val - short_reg[k]);
        }
        __syncthreads();

        // augmentation walk (wave-uniform scalar chain)
        int jj = sink;
        while (true) {
            int kk = jj >> 6, ll = jj & 63;
            int ii = __shfl(path_reg[kk], ll);   // path[jj]
            if (lane == ll) r4c_reg[kk] = ii;    // row4col[jj] = ii
            int nj = col4row[ii];                // old col4row[ii]
            __syncthreads();
            col4row[ii] = jj;                    // all lanes, same data
            __syncthreads();
            jj = nj;
            if (ii == cur) break;
        }
        __syncthreads();
    }

    // ---- output: pairs (pred=col4row[t], truth=t) sorted by pred index ----
    if (lane < NT) {
        int it = col4row[lane];
        int rank = 0;
        for (int t2 = 0; t2 < NT; ++t2) rank += (col4row[t2] < it) ? 1 : 0;
        out[b * 2 * NT + rank] = it;            // row 0: sorted pred indices
        out[b * 2 * NT + NT + rank] = lane;     // row 1: matching truth indices
    }
}

extern "C" void kernel_launch(void* const* d_in, const int* in_sizes, int n_in,
                              void* d_out, int out_size, void* d_ws, size_t ws_size,
                              hipStream_t stream) {
    const float* pred  = (const float*)d_in[0];   // (32, 300, 4) f32
    const float* truth = (const float*)d_in[1];   // (32, 50, 4)  f32
    int* out = (int*)d_out;                       // (32, 2, 50)  int32
    hungarian_kernel<<<32, 64, 0, stream>>>(pred, truth, out);
}

// Round 2
// 131.423 us; speedup vs baseline: 1.3514x; 1.3514x over previous
//
#include <hip/hip_runtime.h>

// Hungarian matcher: B=32 batches, Q=300 preds (cols), T=50 truths (rows).
// One 64-lane wave per batch. Column state (300 cols) distributed across
// lanes in registers, 5 slots/lane (col j owned by lane j&63, slot j>>6).
// JV-style init: u[i] = row min (feasible duals), greedy pre-assignment of
// argmin columns; Dijkstra (successive shortest paths) only for the ~4-8
// rows whose argmin column collides. Exact f64 LSA on bit-identical f32
// costs -> unique optimum == reference assignment.

#define NQ 300
#define NT 50
#define NSLOT 5    // ceil(300/64)
#define STRIDE 301 // pad: gcd(301,32)=1 -> row-scan across lanes conflict-free

__global__ __launch_bounds__(64) void hungarian_kernel(
    const float* __restrict__ pred, const float* __restrict__ truth,
    int* __restrict__ out)
{
#pragma clang fp contract(off)
    const int b = blockIdx.x;
    const int lane = threadIdx.x;

    __shared__ float cost[NT * STRIDE];  // [t][q] padded
    __shared__ double u[NT];
    __shared__ double sh_short[NQ];      // shortest dump for u-update gather
    __shared__ int col4row[NT];

    const float* pb = pred + b * NQ * 4;
    const float* tb = truth + b * NT * 4;

    // ---- cost matrix: C[t][q] = 5*L1 + 2*(-giou), reference op order ----
    // (arithmetic identical to the verified round-1 kernel; only the store
    //  stride changed, which does not affect the computed bits)
    for (int idx = lane; idx < NT * NQ; idx += 64) {
        int t = idx / NQ;
        int q = idx - t * NQ;
        float pcx = pb[q*4+0], pcy = pb[q*4+1], pw = pb[q*4+2], ph = pb[q*4+3];
        float tcx = tb[t*4+0], tcy = tb[t*4+1], tw = tb[t*4+2], th = tb[t*4+3];
        float cb = ((fabsf(pcx-tcx) + fabsf(pcy-tcy)) + fabsf(pw-tw)) + fabsf(ph-th);
        float px1 = pcx - 0.5f*pw, py1 = pcy - 0.5f*ph;
        float px2 = pcx + 0.5f*pw, py2 = pcy + 0.5f*ph;
        float tx1 = tcx - 0.5f*tw, ty1 = tcy - 0.5f*th;
        float tx2 = tcx + 0.5f*tw, ty2 = tcy + 0.5f*th;
        float area1 = (px2-px1)*(py2-py1);
        float area2 = (tx2-tx1)*(ty2-ty1);
        float ltx = fmaxf(px1, tx1), lty = fmaxf(py1, ty1);
        float rbx = fminf(px2, tx2), rby = fminf(py2, ty2);
        float w = fmaxf(rbx-ltx, 0.f), h = fmaxf(rby-lty, 0.f);
        float inter = w*h;
        float uni = (area1 + area2) - inter;
        float iou = inter/uni;
        float ex1 = fminf(px1,tx1), ey1 = fminf(py1,ty1);
        float ex2 = fmaxf(px2,tx2), ey2 = fmaxf(py2,ty2);
        float ew = fmaxf(ex2-ex1, 0.f), eh = fmaxf(ey2-ey1, 0.f);
        float ae = ew*eh;
        float g = iou - (ae - uni)/ae;
        cost[t*STRIDE + q] = 5.0f*cb + 2.0f*(-g);
    }
    if (lane < NT) col4row[lane] = -1;

    // per-lane distributed column state
    double v_reg[NSLOT], short_reg[NSLOT];
    int path_reg[NSLOT], r4c_reg[NSLOT];
    for (int k = 0; k < NSLOT; ++k) { v_reg[k] = 0.0; r4c_reg[k] = -1; }
    __syncthreads();

    // ---- row reduction: u[t] = min_q cost[t][q]; remember argmin ----
    float rm = __builtin_inff();
    int ram = 0;
    if (lane < NT) {
        const float* row = cost + lane * STRIDE;
        for (int c = 0; c < NQ; ++c) {
            float x = row[c];
            if (x < rm) { rm = x; ram = c; }
        }
        u[lane] = (double)rm;   // exact: cast of the f32 min
    }
    __syncthreads();

    // ---- greedy pre-assignment: row t -> its argmin column if free ----
    // assigned edge reduced cost = c - u[t] - 0 = 0 exactly -> CS holds
    unsigned long long pending = 0;
    for (int t = 0; t < NT; ++t) {
        int jstar = __shfl(ram, t);
        int kj = jstar >> 6, lj = jstar & 63;
        int r = __shfl(r4c_reg[kj], lj);
        if (r < 0) {
            if (lane == lj) r4c_reg[kj] = t;
            col4row[t] = jstar;             // all lanes, same value
        } else {
            pending |= 1ull << t;
        }
    }
    __syncthreads();

    // ---- Dijkstra rounds for the pending (collided) rows ----
    while (pending) {
        int cur = __builtin_ctzll(pending);
        pending &= pending - 1;

        unsigned oncol = 0;                 // per-lane: bit k -> col lane+64k
        unsigned long long onrow = 0;       // wave-uniform
        for (int k = 0; k < NSLOT; ++k) { short_reg[k] = __builtin_inf(); path_reg[k] = -1; }
        double min_val = 0.0;
        int i = cur, sink = -1;

        while (sink < 0) {
            onrow |= 1ull << i;
            double u_i = u[i];
            const float* crow = cost + i * STRIDE;
            double bv = __builtin_inf();
            int bj = 0x7fffffff;
            for (int k = 0; k < NSLOT; ++k) {
                int j = lane + (k << 6);
                if (j < NQ && !((oncol >> k) & 1u)) {
                    double d = ((min_val + (double)crow[j]) - u_i) - v_reg[k];
                    if (d < short_reg[k]) { short_reg[k] = d; path_reg[k] = i; }
                    if (short_reg[k] < bv) { bv = short_reg[k]; bj = j; }
                }
            }
            // wave argmin; tie -> smaller column index
            for (int off = 32; off >= 1; off >>= 1) {
                double ov = __shfl_xor(bv, off);
                int oj = __shfl_xor(bj, off);
                if (ov < bv || (ov == bv && oj < bj)) { bv = ov; bj = oj; }
            }
            int j = bj;
            min_val = bv;
            int kj = j >> 6, lj = j & 63;
            if (lane == lj) oncol |= 1u << kj;
            int r = __shfl(r4c_reg[kj], lj);   // row4col[j]
            if (r < 0) sink = j; else i = r;
        }

        // dump shortest for the u-update gather
        for (int k = 0; k < NSLOT; ++k) {
            int j = lane + (k << 6);
            if (j < NQ) sh_short[j] = short_reg[k];
        }
        __syncthreads();

        // u updates
        if (lane < NT) {
            if (lane == cur) {
                u[lane] = u[lane] + min_val;
            } else if ((onrow >> lane) & 1ull) {
                int c = col4row[lane];
                u[lane] = u[lane] + (min_val - sh_short[c]);
            }
        }
        // v updates: lane-local columns marked on_col
        for (int k = 0; k < NSLOT; ++k) {
            int j = lane + (k << 6);
            if (j < NQ && ((oncol >> k) & 1u))
                v_reg[k] = v_reg[k] - (min_val - short_reg[k]);
        }
        __syncthreads();

        // augmentation walk (wave-uniform scalar chain)
        int jj = sink;
        while (true) {
            int kk = jj >> 6, ll = jj & 63;
            int ii = __shfl(path_reg[kk], ll);   // path[jj]
            if (lane == ll) r4c_reg[kk] = ii;    // row4col[jj] = ii
            int nj = col4row[ii];
            __syncthreads();
            col4row[ii] = jj;
            __syncthreads();
            jj = nj;
            if (ii == cur) break;
        }
        __syncthreads();
    }

    // ---- output: pairs (pred=col4row[t], truth=t) sorted by pred index ----
    if (lane < NT) {
        int it = col4row[lane];
        int rank = 0;
        for (int t2 = 0; t2 < NT; ++t2) rank += (col4row[t2] < it) ? 1 : 0;
        out[b * 2 * NT + rank] = it;            // row 0: sorted pred indices
        out[b * 2 * NT + NT + rank] = lane;     // row 1: matching truth indices
    }
}

extern "C" void kernel_launch(void* const* d_in, const int* in_sizes, int n_in,
                              void* d_out, int out_size, void* d_ws, size_t ws_size,
                              hipStream_t stream) {
    const float* pred  = (const float*)d_in[0];   // (32, 300, 4) f32
    const float* truth = (const float*)d_in[1];   // (32, 50, 4)  f32
    int* out = (int*)d_out;                       // (32, 2, 50)  int32
    hungarian_kernel<<<32, 64, 0, stream>>>(pred, truth, out);
}

// Round 3
// 97.752 us; speedup vs baseline: 1.8169x; 1.3445x over previous
//
#include <hip/hip_runtime.h>

// Hungarian matcher: B=32 batches, Q=300 preds (cols), T=50 truths (rows).
// 256 threads/block: 4 waves build the cost matrix; wave 0 then solves the
// LSA with all state in distributed registers (no __syncthreads in solver).
// Pipeline: row reduction -> greedy (atomicMin) -> JV augmenting-row-
// reduction (<=2 attempts/row) -> Dijkstra fallback. Exact f64 duals;
// argmin via packed monotone-u64 keys (tie -> smallest column).

#define NQ 300
#define NT 50
#define NSLOT 5    // ceil(300/64)
#define STRIDE 301 // pad so row scans across lanes spread banks
#define NTHREADS 256

typedef unsigned long long u64_t;

// monotone total-order key for f64 (handles negatives), low 9 bits = col idx.
// Comparison quantized at 2^-43 relative; exact value re-fetched afterwards.
__device__ __forceinline__ u64_t pack_key(double d, int j) {
    u64_t u = __builtin_bit_cast(u64_t, d);
    u ^= (u64_t)((long long)u >> 63) | 0x8000000000000000ull;
    return (u & ~511ull) | (u64_t)(unsigned)j;
}
__device__ __forceinline__ u64_t shflx_u64(u64_t x, int off) {
    double d = __builtin_bit_cast(double, x);
    d = __shfl_xor(d, off);
    return __builtin_bit_cast(u64_t, d);
}
// single-wave LDS producer->consumer: per-wave DS ops are in-order; this
// just stops the compiler from reordering across it.
__device__ __forceinline__ void wave_sync() { __builtin_amdgcn_wave_barrier(); }

// unrolled dynamic-index selects (avoid scratch-spilled register arrays)
#define SEL5(res, a, kidx) do { (res) = a[0]; \
    if ((kidx) == 1) (res) = a[1]; if ((kidx) == 2) (res) = a[2]; \
    if ((kidx) == 3) (res) = a[3]; if ((kidx) == 4) (res) = a[4]; } while (0)
#define SET5(a, kidx, val) do { \
    if ((kidx) == 0) a[0] = (val); if ((kidx) == 1) a[1] = (val); \
    if ((kidx) == 2) a[2] = (val); if ((kidx) == 3) a[3] = (val); \
    if ((kidx) == 4) a[4] = (val); } while (0)

__global__ __launch_bounds__(NTHREADS) void hungarian_kernel(
    const float* __restrict__ pred, const float* __restrict__ truth,
    int* __restrict__ out)
{
#pragma clang fp contract(off)
    const int b = blockIdx.x;
    const int tid = threadIdx.x;
    const int lane = tid & 63;
    const int wav = tid >> 6;

    __shared__ float cost[NT * STRIDE];  // 60200 B
    __shared__ int claim[NQ];            // 1200 B
    __shared__ double sh_short[NQ];      // 2400 B
    __shared__ int sh_c4r[NT];           // 200 B   (total 64000 B)

    const float* pb = pred + b * NQ * 4;
    const float* tb = truth + b * NT * 4;

    // ---- phase 1: cost matrix, all 4 waves (reference op order, no fma) ----
    for (int idx = tid; idx < NT * NQ; idx += NTHREADS) {
        int t = idx / NQ;
        int q = idx - t * NQ;
        float pcx = pb[q*4+0], pcy = pb[q*4+1], pw = pb[q*4+2], ph = pb[q*4+3];
        float tcx = tb[t*4+0], tcy = tb[t*4+1], tw = tb[t*4+2], th = tb[t*4+3];
        float cb = ((fabsf(pcx-tcx) + fabsf(pcy-tcy)) + fabsf(pw-tw)) + fabsf(ph-th);
        float px1 = pcx - 0.5f*pw, py1 = pcy - 0.5f*ph;
        float px2 = pcx + 0.5f*pw, py2 = pcy + 0.5f*ph;
        float tx1 = tcx - 0.5f*tw, ty1 = tcy - 0.5f*th;
        float tx2 = tcx + 0.5f*tw, ty2 = tcy + 0.5f*th;
        float area1 = (px2-px1)*(py2-py1);
        float area2 = (tx2-tx1)*(ty2-ty1);
        float ltx = fmaxf(px1, tx1), lty = fmaxf(py1, ty1);
        float rbx = fminf(px2, tx2), rby = fminf(py2, ty2);
        float w = fmaxf(rbx-ltx, 0.f), h = fmaxf(rby-lty, 0.f);
        float inter = w*h;
        float uni = (area1 + area2) - inter;
        float iou = inter/uni;
        float ex1 = fminf(px1,tx1), ey1 = fminf(py1,ty1);
        float ex2 = fmaxf(px2,tx2), ey2 = fmaxf(py2,ty2);
        float ew = fmaxf(ex2-ex1, 0.f), eh = fmaxf(ey2-ey1, 0.f);
        float ae = ew*eh;
        float g = iou - (ae - uni)/ae;
        cost[t*STRIDE + q] = 5.0f*cb + 2.0f*(-g);
    }
    for (int j = tid; j < NQ; j += NTHREADS) claim[j] = 0x7fffffff;
    __syncthreads();

    // ---- phase 2: row reduction (rows live on wave-0 lanes 0..49) ----
    float rm = __builtin_inff();
    int ram = 0;
    if (tid < NT) {
        const float* row = cost + tid * STRIDE;
        for (int c = 0; c < NQ; ++c) {
            float x = row[c];
            if (x < rm) { rm = x; ram = c; }
        }
        atomicMin(&claim[ram], tid);   // greedy claim: smallest row wins
    }
    __syncthreads();
    if (wav != 0) return;              // no barriers below this point

    // ---- wave-0 distributed solver state ----
    double u_reg = (tid < NT) ? (double)rm : 0.0;  // lane t: u[t]
    int c4r = -1;                                  // lane t: col4row[t]
    if (tid < NT && claim[ram] == tid) c4r = ram;
    double v_reg[NSLOT];
    int r4c_reg[NSLOT];
#pragma unroll
    for (int k = 0; k < NSLOT; ++k) {
        int j = lane + (k << 6);
        v_reg[k] = 0.0;
        int cl = (j < NQ) ? claim[j] : 0x7fffffff;
        r4c_reg[k] = (cl != 0x7fffffff) ? cl : -1;
    }
    u64_t arr = __ballot(tid < NT && c4r < 0);   // rows needing work
    u64_t att1 = 0, att2 = 0, dij = 0;

    // ---- phase 3: JV augmenting row reduction (<=2 requeues per row) ----
    while (arr) {
        int i = __builtin_ctzll(arr);
        arr &= arr - 1;
        const float* crow = cost + i * STRIDE;
        u64_t k1 = ~0ull;
        double v1 = __builtin_inf(), v2 = __builtin_inf();
#pragma unroll
        for (int k = 0; k < NSLOT; ++k) {
            int j = lane + (k << 6);
            if (j < NQ) {
                double m = (double)crow[j] - v_reg[k];
                u64_t kk = pack_key(m, j);
                if (kk < k1) { v2 = v1; v1 = m; k1 = kk; }
                else if (m < v2) { v2 = m; }
            }
        }
#pragma unroll
        for (int off = 32; off >= 1; off >>= 1) {
            u64_t ok = shflx_u64(k1, off);
            double ov1 = __shfl_xor(v1, off);
            double ov2 = __shfl_xor(v2, off);
            double nv2 = fmin(fmin(v2, ov2), fmax(v1, ov1));
            if (ok < k1) { k1 = ok; v1 = ov1; }
            v2 = nv2;
        }
        int j1 = (int)(k1 & 511ull);
        int kj = j1 >> 6, lj = j1 & 63;
        int rsel; SEL5(rsel, r4c_reg, kj);
        int r = __shfl(rsel, lj);
        if (r < 0) {
            if (lane == lj) SET5(r4c_reg, kj, i);
            if (lane == i) { c4r = j1; u_reg = v1; }
        } else {
            double cij = (double)crow[j1];       // uniform broadcast read
            if (lane == lj) { SET5(r4c_reg, kj, i); SET5(v_reg, kj, cij - v2); }
            if (lane == i) { c4r = j1; u_reg = v2; }
            if (lane == r) c4r = -1;
            u64_t rb = 1ull << r;
            if (!(att1 & rb))      { att1 |= rb; arr |= rb; }
            else if (!(att2 & rb)) { att2 |= rb; arr |= rb; }
            else                   { dij |= rb; }
        }
    }

    // ---- phase 4: Dijkstra (successive shortest paths) for leftovers ----
    while (dij) {
        int cur = __builtin_ctzll(dij);
        dij &= dij - 1;
        unsigned oncol = 0;
        u64_t onrow = 0;
        double short_reg[NSLOT];
        int path_reg[NSLOT];
#pragma unroll
        for (int k = 0; k < NSLOT; ++k) { short_reg[k] = __builtin_inf(); path_reg[k] = -1; }
        double min_val = 0.0;
        int i = cur, sink = -1;

        while (sink < 0) {
            onrow |= 1ull << i;
            double u_i = __shfl(u_reg, i);
            const float* crow = cost + i * STRIDE;
            u64_t bk = ~0ull;
#pragma unroll
            for (int k = 0; k < NSLOT; ++k) {
                int j = lane + (k << 6);
                if (j < NQ && !((oncol >> k) & 1u)) {
                    double d = ((min_val + (double)crow[j]) - u_i) - v_reg[k];
                    if (d < short_reg[k]) { short_reg[k] = d; path_reg[k] = i; }
                    u64_t kk = pack_key(short_reg[k], j);
                    if (kk < bk) bk = kk;
                }
            }
#pragma unroll
            for (int off = 32; off >= 1; off >>= 1) {
                u64_t ok = shflx_u64(bk, off);
                if (ok < bk) bk = ok;
            }
            int j = (int)(bk & 511ull);
            int kj = j >> 6, lj = j & 63;
            double ssel; SEL5(ssel, short_reg, kj);
            min_val = __shfl(ssel, lj);          // exact winning value
            if (lane == lj) oncol |= 1u << kj;
            int rsel; SEL5(rsel, r4c_reg, kj);
            int r = __shfl(rsel, lj);
            if (r < 0) sink = j; else i = r;
        }

        // dump shortest for the u-update gather (wave-local LDS round trip)
#pragma unroll
        for (int k = 0; k < NSLOT; ++k) {
            int j = lane + (k << 6);
            if (j < NQ) sh_short[j] = short_reg[k];
        }
        wave_sync();
        double ss = (tid < NT && c4r >= 0) ? sh_short[c4r] : 0.0;
        if (tid < NT) {
            if (tid == cur) u_reg = u_reg + min_val;
            else if ((onrow >> tid) & 1ull) u_reg = u_reg + (min_val - ss);
        }
#pragma unroll
        for (int k = 0; k < NSLOT; ++k) {
            int j = lane + (k << 6);
            if (j < NQ && ((oncol >> k) & 1u))
                v_reg[k] = v_reg[k] - (min_val - short_reg[k]);
        }

        // augmentation walk: registers + shuffles only
        int jj = sink;
        while (true) {
            int kk2 = jj >> 6, ll = jj & 63;
            int psel; SEL5(psel, path_reg, kk2);
            int ii = __shfl(psel, ll);
            if (lane == ll) SET5(r4c_reg, kk2, ii);
            int nj = __shfl(c4r, ii);            // old col4row[ii]
            if (lane == ii) c4r = jj;
            jj = nj;
            if (ii == cur) break;
        }
    }

    // ---- output: pairs (pred=col4row[t], truth=t) sorted by pred index ----
    if (tid < NT) sh_c4r[tid] = c4r;
    wave_sync();
    if (tid < NT) {
        int it = c4r;
        int rank = 0;
        for (int t2 = 0; t2 < NT; ++t2) rank += (sh_c4r[t2] < it) ? 1 : 0;
        out[b * 2 * NT + rank] = it;             // row 0: sorted pred indices
        out[b * 2 * NT + NT + rank] = tid;       // row 1: matching truth indices
    }
}

extern "C" void kernel_launch(void* const* d_in, const int* in_sizes, int n_in,
                              void* d_out, int out_size, void* d_ws, size_t ws_size,
                              hipStream_t stream) {
    const float* pred  = (const float*)d_in[0];   // (32, 300, 4) f32
    const float* truth = (const float*)d_in[1];   // (32, 50, 4)  f32
    int* out = (int*)d_out;                       // (32, 2, 50)  int32
    hungarian_kernel<<<32, NTHREADS, 0, stream>>>(pred, truth, out);
}

// Round 4
// 93.950 us; speedup vs baseline: 1.8904x; 1.0405x over previous
//
#include <hip/hip_runtime.h>

// Hungarian matcher: B=32 batches, Q=300 preds (cols), T=50 truths (rows).
// 256 threads/block: 4 waves build the cost matrix; wave 0 solves the LSA
// with all state in distributed registers. Cross-lane traffic runs on the
// DPP network (VALU latency) + v_readlane for uniform-index fetches --
// no ds-swizzle butterflies (at 1 wave/SIMD each ds op is ~120 cy).
// Pipeline: row reduction -> greedy (atomicMin) -> JV augmenting-row-
// reduction (<=4 requeues/row) -> Dijkstra fallback. Exact f64 duals;
// argmin keys quantized at 2^-43 rel (ties measure-zero), values exact.

#define NQ 300
#define NT 50
#define NSLOT 5    // ceil(300/64)
#define STRIDE 301
#define NTHREADS 256
#define ARR_CAP 4

typedef unsigned long long u64_t;

__device__ __forceinline__ u64_t minu64(u64_t a, u64_t b) { return a < b ? a : b; }

// monotone total-order mapping f64 <-> u64 (handles negatives)
__device__ __forceinline__ u64_t f64_key(double d) {
    u64_t u = __builtin_bit_cast(u64_t, d);
    u ^= (u64_t)((long long)u >> 63) | 0x8000000000000000ull;
    return u;
}
__device__ __forceinline__ double key_f64(u64_t k) {
    u64_t u = (k >> 63) ? (k ^ 0x8000000000000000ull) : ~k;
    return __builtin_bit_cast(double, u);
}
// low 9 bits = column index (unique winner; tie -> smaller column)
__device__ __forceinline__ u64_t pack_key(double d, int j) {
    return (f64_key(d) & ~511ull) | (u64_t)(unsigned)j;
}

template<int CTRL, int RMASK>
__device__ __forceinline__ u64_t dpp_u64(u64_t x) {
    int lo = (int)(unsigned)(x & 0xffffffffull);
    int hi = (int)(unsigned)(x >> 32);
    int plo = __builtin_amdgcn_update_dpp(lo, lo, CTRL, RMASK, 0xf, false);
    int phi = __builtin_amdgcn_update_dpp(hi, hi, CTRL, RMASK, 0xf, false);
    return ((u64_t)(unsigned)phi << 32) | (u64_t)(unsigned)plo;
}

// full-wave u64 min, result broadcast to all lanes (VALU/DPP only)
__device__ __forceinline__ u64_t wave_min_u64(u64_t k) {
    k = minu64(k, dpp_u64<0x121, 0xf>(k));  // row_ror:1  (16-lane rows)
    k = minu64(k, dpp_u64<0x122, 0xf>(k));  // row_ror:2
    k = minu64(k, dpp_u64<0x124, 0xf>(k));  // row_ror:4
    k = minu64(k, dpp_u64<0x128, 0xf>(k));  // row_ror:8
    k = minu64(k, dpp_u64<0x142, 0xa>(k));  // row_bcast15 -> rows 1,3
    k = minu64(k, dpp_u64<0x143, 0xc>(k));  // row_bcast31 -> rows 2,3
    int lo = __builtin_amdgcn_readlane((int)(unsigned)(k & 0xffffffffull), 63);
    int hi = __builtin_amdgcn_readlane((int)(unsigned)(k >> 32), 63);
    return ((u64_t)(unsigned)hi << 32) | (u64_t)(unsigned)lo;
}

__device__ __forceinline__ double readlane_f64(double x, int l) {
    u64_t u = __builtin_bit_cast(u64_t, x);
    int lo = __builtin_amdgcn_readlane((int)(unsigned)(u & 0xffffffffull), l);
    int hi = __builtin_amdgcn_readlane((int)(unsigned)(u >> 32), l);
    return __builtin_bit_cast(double, ((u64_t)(unsigned)hi << 32) | (u64_t)(unsigned)lo);
}

__device__ __forceinline__ void wave_sync() { __builtin_amdgcn_wave_barrier(); }

// unrolled dynamic-index selects (avoid scratch-spilled register arrays)
#define SEL5(res, a, kidx) do { (res) = a[0]; \
    if ((kidx) == 1) (res) = a[1]; if ((kidx) == 2) (res) = a[2]; \
    if ((kidx) == 3) (res) = a[3]; if ((kidx) == 4) (res) = a[4]; } while (0)
#define SET5(a, kidx, val) do { \
    if ((kidx) == 0) a[0] = (val); if ((kidx) == 1) a[1] = (val); \
    if ((kidx) == 2) a[2] = (val); if ((kidx) == 3) a[3] = (val); \
    if ((kidx) == 4) a[4] = (val); } while (0)

__global__ __launch_bounds__(NTHREADS) void hungarian_kernel(
    const float* __restrict__ pred, const float* __restrict__ truth,
    int* __restrict__ out)
{
#pragma clang fp contract(off)
    const int b = blockIdx.x;
    const int tid = threadIdx.x;
    const int lane = tid & 63;
    const int wav = tid >> 6;

    __shared__ float cost[NT * STRIDE];  // 60200 B
    __shared__ int claim[NQ];            // 1200 B
    __shared__ double sh_short[NQ];      // 2400 B
    __shared__ int sh_c4r[NT];           // 200 B  (total 64000 B)

    const float* pb = pred + b * NQ * 4;
    const float* tb = truth + b * NT * 4;

    // ---- phase 1: cost matrix, all 4 waves (reference op order, no fma) ----
    for (int idx = tid; idx < NT * NQ; idx += NTHREADS) {
        int t = idx / NQ;
        int q = idx - t * NQ;
        float pcx = pb[q*4+0], pcy = pb[q*4+1], pw = pb[q*4+2], ph = pb[q*4+3];
        float tcx = tb[t*4+0], tcy = tb[t*4+1], tw = tb[t*4+2], th = tb[t*4+3];
        float cb = ((fabsf(pcx-tcx) + fabsf(pcy-tcy)) + fabsf(pw-tw)) + fabsf(ph-th);
        float px1 = pcx - 0.5f*pw, py1 = pcy - 0.5f*ph;
        float px2 = pcx + 0.5f*pw, py2 = pcy + 0.5f*ph;
        float tx1 = tcx - 0.5f*tw, ty1 = tcy - 0.5f*th;
        float tx2 = tcx + 0.5f*tw, ty2 = tcy + 0.5f*th;
        float area1 = (px2-px1)*(py2-py1);
        float area2 = (tx2-tx1)*(ty2-ty1);
        float ltx = fmaxf(px1, tx1), lty = fmaxf(py1, ty1);
        float rbx = fminf(px2, tx2), rby = fminf(py2, ty2);
        float w = fmaxf(rbx-ltx, 0.f), h = fmaxf(rby-lty, 0.f);
        float inter = w*h;
        float uni = (area1 + area2) - inter;
        float iou = inter/uni;
        float ex1 = fminf(px1,tx1), ey1 = fminf(py1,ty1);
        float ex2 = fmaxf(px2,tx2), ey2 = fmaxf(py2,ty2);
        float ew = fmaxf(ex2-ex1, 0.f), eh = fmaxf(ey2-ey1, 0.f);
        float ae = ew*eh;
        float g = iou - (ae - uni)/ae;
        cost[t*STRIDE + q] = 5.0f*cb + 2.0f*(-g);
    }
    for (int j = tid; j < NQ; j += NTHREADS) claim[j] = 0x7fffffff;
    __syncthreads();

    // ---- phase 2: row min via 4 independent chains (rows on lanes 0..49) ----
    float rm = __builtin_inff();
    int ram = 0;
    if (tid < NT) {
        const float* row = cost + tid * STRIDE;
        float m0 = __builtin_inff(), m1 = m0, m2 = m0, m3 = m0;
        int a0 = 0, a1 = 0, a2 = 0, a3 = 0;
        for (int c = 0; c < NQ; c += 4) {
            float x0 = row[c], x1 = row[c+1], x2 = row[c+2], x3 = row[c+3];
            if (x0 < m0) { m0 = x0; a0 = c; }
            if (x1 < m1) { m1 = x1; a1 = c+1; }
            if (x2 < m2) { m2 = x2; a2 = c+2; }
            if (x3 < m3) { m3 = x3; a3 = c+3; }
        }
        rm = m0; ram = a0;
        if (m1 < rm || (m1 == rm && a1 < ram)) { rm = m1; ram = a1; }
        if (m2 < rm || (m2 == rm && a2 < ram)) { rm = m2; ram = a2; }
        if (m3 < rm || (m3 == rm && a3 < ram)) { rm = m3; ram = a3; }
        atomicMin(&claim[ram], tid);   // greedy claim: smallest row wins
    }
    __syncthreads();
    if (wav != 0) return;              // no barriers below this point

    // ---- wave-0 distributed solver state ----
    double u_reg = (tid < NT) ? (double)rm : 0.0;  // lane t: u[t]
    int c4r = -1;                                  // lane t: col4row[t]
    if (tid < NT && claim[ram] == tid) c4r = ram;
    double v_reg[NSLOT];
    int r4c_reg[NSLOT];
#pragma unroll
    for (int k = 0; k < NSLOT; ++k) {
        int j = lane + (k << 6);
        v_reg[k] = 0.0;
        int cl = (j < NQ) ? claim[j] : 0x7fffffff;
        r4c_reg[k] = (cl != 0x7fffffff) ? cl : -1;
    }
    int att_cnt = 0;                               // lane t: requeues of row t
    u64_t arr = __ballot(tid < NT && c4r < 0);
    u64_t dij = 0;

    // ---- phase 3: JV augmenting row reduction (<= ARR_CAP requeues/row) ----
    while (arr) {
        int i = __builtin_ctzll(arr);
        arr &= arr - 1;
        const float* crow = cost + i * STRIDE;
        u64_t k1 = ~0ull;
        double v1 = __builtin_inf(), v2 = __builtin_inf();
#pragma unroll
        for (int k = 0; k < NSLOT; ++k) {
            int j = lane + (k << 6);
            if (j < NQ) {
                double m = (double)crow[j] - v_reg[k];
                u64_t kk = pack_key(m, j);
                if (kk < k1) { v2 = v1; v1 = m; k1 = kk; }
                else if (m < v2) { v2 = m; }
            }
        }
        u64_t kmin = wave_min_u64(k1);             // uniform
        int j1 = (int)(kmin & 511ull);
        int kj = j1 >> 6, lj = j1 & 63;
        double v1g = readlane_f64(v1, lj);         // exact winning value
        // exact global second-min: winner lane contributes its v2, rest v1
        double cand = (lane == lj) ? v2 : v1;
        double v2g = key_f64(wave_min_u64(f64_key(cand)));
        int rsel; SEL5(rsel, r4c_reg, kj);
        int r = __builtin_amdgcn_readlane(rsel, lj);
        if (r < 0) {
            if (lane == lj) SET5(r4c_reg, kj, i);
            if (lane == i) { c4r = j1; u_reg = v1g; }
        } else {
            double cij = (double)crow[j1];         // uniform broadcast read
            if (lane == lj) { SET5(r4c_reg, kj, i); SET5(v_reg, kj, cij - v2g); }
            if (lane == i) { c4r = j1; u_reg = v2g; }
            if (lane == r) { c4r = -1; att_cnt++; }
            int ac = __builtin_amdgcn_readlane(att_cnt, r);
            u64_t rb = 1ull << r;
            if (ac <= ARR_CAP) arr |= rb; else dij |= rb;
        }
    }

    // ---- phase 4: Dijkstra (successive shortest paths) for leftovers ----
    while (dij) {
        int cur = __builtin_ctzll(dij);
        dij &= dij - 1;
        unsigned oncol = 0;
        u64_t onrow = 0;
        double short_reg[NSLOT];
        int path_reg[NSLOT];
#pragma unroll
        for (int k = 0; k < NSLOT; ++k) { short_reg[k] = __builtin_inf(); path_reg[k] = -1; }
        double min_val = 0.0;
        int i = cur, sink = -1;

        while (sink < 0) {
            onrow |= 1ull << i;
            double u_i = readlane_f64(u_reg, i);
            const float* crow = cost + i * STRIDE;
            u64_t bk = ~0ull;
#pragma unroll
            for (int k = 0; k < NSLOT; ++k) {
                int j = lane + (k << 6);
                if (j < NQ && !((oncol >> k) & 1u)) {
                    double d = ((min_val + (double)crow[j]) - u_i) - v_reg[k];
                    if (d < short_reg[k]) { short_reg[k] = d; path_reg[k] = i; }
                    u64_t kk = pack_key(short_reg[k], j);
                    if (kk < bk) bk = kk;
                }
            }
            bk = wave_min_u64(bk);                 // uniform
            int j = (int)(bk & 511ull);
            int kj = j >> 6, lj = j & 63;
            double ssel; SEL5(ssel, short_reg, kj);
            min_val = readlane_f64(ssel, lj);      // exact winning value
            if (lane == lj) oncol |= 1u << kj;
            int rsel; SEL5(rsel, r4c_reg, kj);
            int r = __builtin_amdgcn_readlane(rsel, lj);
            if (r < 0) sink = j; else i = r;
        }

        // dump shortest for the u-update gather (per-lane variable index)
#pragma unroll
        for (int k = 0; k < NSLOT; ++k) {
            int j = lane + (k << 6);
            if (j < NQ) sh_short[j] = short_reg[k];
        }
        wave_sync();
        double ss = (tid < NT && c4r >= 0) ? sh_short[c4r] : 0.0;
        if (tid < NT) {
            if (tid == cur) u_reg = u_reg + min_val;
            else if ((onrow >> tid) & 1ull) u_reg = u_reg + (min_val - ss);
        }
#pragma unroll
        for (int k = 0; k < NSLOT; ++k) {
            int j = lane + (k << 6);
            if (j < NQ && ((oncol >> k) & 1u))
                v_reg[k] = v_reg[k] - (min_val - short_reg[k]);
        }

        // augmentation walk: registers + readlane only
        int jj = sink;
        while (true) {
            int kk2 = jj >> 6, ll = jj & 63;
            int psel; SEL5(psel, path_reg, kk2);
            int ii = __builtin_amdgcn_readlane(psel, ll);
            if (lane == ll) SET5(r4c_reg, kk2, ii);
            int nj = __builtin_amdgcn_readlane(c4r, ii);  // old col4row[ii]
            if (lane == ii) c4r = jj;
            jj = nj;
            if (ii == cur) break;
        }
    }

    // ---- output: pairs (pred=col4row[t], truth=t) sorted by pred index ----
    if (tid < NT) sh_c4r[tid] = c4r;
    wave_sync();
    if (tid < NT) {
        int it = c4r;
        int rank = 0;
        for (int t2 = 0; t2 < NT; ++t2) rank += (sh_c4r[t2] < it) ? 1 : 0;
        out[b * 2 * NT + rank] = it;             // row 0: sorted pred indices
        out[b * 2 * NT + NT + rank] = tid;       // row 1: matching truth indices
    }
}

extern "C" void kernel_launch(void* const* d_in, const int* in_sizes, int n_in,
                              void* d_out, int out_size, void* d_ws, size_t ws_size,
                              hipStream_t stream) {
    const float* pred  = (const float*)d_in[0];   // (32, 300, 4) f32
    const float* truth = (const float*)d_in[1];   // (32, 50, 4)  f32
    int* out = (int*)d_out;                       // (32, 2, 50)  int32
    hungarian_kernel<<<32, NTHREADS, 0, stream>>>(pred, truth, out);
}

// Round 5
// 88.216 us; speedup vs baseline: 2.0133x; 1.0650x over previous
//
#include <hip/hip_runtime.h>

// Hungarian matcher: B=32 batches, Q=300 preds (cols), T=50 truths (rows).
// 256 threads/block: 4 waves build the cost matrix + segmented row-min;
// wave 0 solves the LSA with all state in distributed registers.
// __launch_bounds__(256,1): 1 wave/SIMD -> ~512 VGPR budget, NO scratch
// spills (R3/R4 spilled solver arrays: WRITE_SIZE 53KB vs 13KB real).
// Cross-lane traffic: DPP joint (key,min1,min2) reduction + v_readlane.
// Pipeline: row reduction -> greedy (atomicMin) -> JV augmenting-row-
// reduction (<=6 requeues/row) -> Dijkstra fallback. Exact f64 duals;
// argmin keys quantized at 2^-43 rel (ties measure-zero), values exact.

#define NQ 300
#define NT 50
#define NSLOT 5    // ceil(300/64)
#define STRIDE 301
#define NTHREADS 256
#define ARR_CAP 6

typedef unsigned long long u64_t;

__device__ __forceinline__ u64_t minu64(u64_t a, u64_t b) { return a < b ? a : b; }

// monotone total-order mapping f64 -> u64 (handles negatives)
__device__ __forceinline__ u64_t f64_key(double d) {
    u64_t u = __builtin_bit_cast(u64_t, d);
    u ^= (u64_t)((long long)u >> 63) | 0x8000000000000000ull;
    return u;
}
// low 9 bits = column index (unique winner; tie -> smaller column)
__device__ __forceinline__ u64_t pack_key(double d, int j) {
    return (f64_key(d) & ~511ull) | (u64_t)(unsigned)j;
}

template<int CTRL, int RMASK>
__device__ __forceinline__ u64_t dpp_u64(u64_t x) {
    int lo = (int)(unsigned)(x & 0xffffffffull);
    int hi = (int)(unsigned)(x >> 32);
    int plo = __builtin_amdgcn_update_dpp(lo, lo, CTRL, RMASK, 0xf, false);
    int phi = __builtin_amdgcn_update_dpp(hi, hi, CTRL, RMASK, 0xf, false);
    return ((u64_t)(unsigned)phi << 32) | (u64_t)(unsigned)plo;
}
template<int CTRL, int RMASK>
__device__ __forceinline__ double dpp_f64(double x) {
    return __builtin_bit_cast(double, dpp_u64<CTRL, RMASK>(__builtin_bit_cast(u64_t, x)));
}

__device__ __forceinline__ u64_t readlane_u64(u64_t u, int l) {
    int lo = __builtin_amdgcn_readlane((int)(unsigned)(u & 0xffffffffull), l);
    int hi = __builtin_amdgcn_readlane((int)(unsigned)(u >> 32), l);
    return ((u64_t)(unsigned)hi << 32) | (u64_t)(unsigned)lo;
}
__device__ __forceinline__ double readlane_f64(double x, int l) {
    return __builtin_bit_cast(double, readlane_u64(__builtin_bit_cast(u64_t, x), l));
}

// full-wave u64 min, result broadcast to all lanes (VALU/DPP only)
__device__ __forceinline__ u64_t wave_min_u64(u64_t k) {
    k = minu64(k, dpp_u64<0x121, 0xf>(k));  // row_ror:1 (16-lane rows)
    k = minu64(k, dpp_u64<0x122, 0xf>(k));  // row_ror:2
    k = minu64(k, dpp_u64<0x124, 0xf>(k));  // row_ror:4
    k = minu64(k, dpp_u64<0x128, 0xf>(k));  // row_ror:8
    k = minu64(k, dpp_u64<0x142, 0xa>(k));  // row_bcast15 -> rows 1,3
    k = minu64(k, dpp_u64<0x143, 0xc>(k));  // row_bcast31 -> rows 2,3
    return readlane_u64(k, 63);
}

__device__ __forceinline__ void wave_sync() { __builtin_amdgcn_wave_barrier(); }

// unrolled dynamic-index selects
#define SEL5(res, a, kidx) do { (res) = a[0]; \
    if ((kidx) == 1) (res) = a[1]; if ((kidx) == 2) (res) = a[2]; \
    if ((kidx) == 3) (res) = a[3]; if ((kidx) == 4) (res) = a[4]; } while (0)
#define SET5(a, kidx, val) do { \
    if ((kidx) == 0) a[0] = (val); if ((kidx) == 1) a[1] = (val); \
    if ((kidx) == 2) a[2] = (val); if ((kidx) == 3) a[3] = (val); \
    if ((kidx) == 4) a[4] = (val); } while (0)

// joint (key,min1,min2) reduction step: merge neighbor's (k1,v1,v2).
// Masked-out rows self-merge (v2 <- v1) but their values are never read.
#define JSTEP(CTRL, RMASK) do { \
    u64_t ok = dpp_u64<CTRL, RMASK>(k1); \
    double ov1 = dpp_f64<CTRL, RMASK>(v1); \
    double ov2 = dpp_f64<CTRL, RMASK>(v2); \
    double lose = (ok < k1) ? v1 : ov1; \
    v2 = fmin(fmin(v2, ov2), lose); \
    if (ok < k1) { k1 = ok; v1 = ov1; } \
} while (0)

__global__ __launch_bounds__(NTHREADS, 1) void hungarian_kernel(
    const float* __restrict__ pred, const float* __restrict__ truth,
    int* __restrict__ out)
{
#pragma clang fp contract(off)
    const int b = blockIdx.x;
    const int tid = threadIdx.x;
    const int lane = tid & 63;
    const int wav = tid >> 6;

    __shared__ float cost[NT * STRIDE];  // 60200 B
    __shared__ int claim[NQ];            // 1200 B
    __shared__ double sh_short[NQ];      // 2400 B (phase2 reuses as scratch)
    __shared__ int sh_c4r[NT];           // 200 B  (total 64000 B)

    const float* pb = pred + b * NQ * 4;
    const float* tb = truth + b * NT * 4;

    // ---- phase 1: cost matrix, all 4 waves (reference op order, no fma) ----
    for (int idx = tid; idx < NT * NQ; idx += NTHREADS) {
        int t = idx / NQ;
        int q = idx - t * NQ;
        float pcx = pb[q*4+0], pcy = pb[q*4+1], pw = pb[q*4+2], ph = pb[q*4+3];
        float tcx = tb[t*4+0], tcy = tb[t*4+1], tw = tb[t*4+2], th = tb[t*4+3];
        float cb = ((fabsf(pcx-tcx) + fabsf(pcy-tcy)) + fabsf(pw-tw)) + fabsf(ph-th);
        float px1 = pcx - 0.5f*pw, py1 = pcy - 0.5f*ph;
        float px2 = pcx + 0.5f*pw, py2 = pcy + 0.5f*ph;
        float tx1 = tcx - 0.5f*tw, ty1 = tcy - 0.5f*th;
        float tx2 = tcx + 0.5f*tw, ty2 = tcy + 0.5f*th;
        float area1 = (px2-px1)*(py2-py1);
        float area2 = (tx2-tx1)*(ty2-ty1);
        float ltx = fmaxf(px1, tx1), lty = fmaxf(py1, ty1);
        float rbx = fminf(px2, tx2), rby = fminf(py2, ty2);
        float w = fmaxf(rbx-ltx, 0.f), h = fmaxf(rby-lty, 0.f);
        float inter = w*h;
        float uni = (area1 + area2) - inter;
        float iou = inter/uni;
        float ex1 = fminf(px1,tx1), ey1 = fminf(py1,ty1);
        float ex2 = fmaxf(px2,tx2), ey2 = fmaxf(py2,ty2);
        float ew = fmaxf(ex2-ex1, 0.f), eh = fmaxf(ey2-ey1, 0.f);
        float ae = ew*eh;
        float g = iou - (ae - uni)/ae;
        cost[t*STRIDE + q] = 5.0f*cb + 2.0f*(-g);
    }
    for (int j = tid; j < NQ; j += NTHREADS) claim[j] = 0x7fffffff;
    __syncthreads();

    // ---- phase 2a: segmented row-min partials (200 threads, 75 cols each) ----
    float* smin = (float*)sh_short;          // [4][50] f32 partial mins
    int* samin = (int*)(smin + 200);         // [4][50] argmins (1600 B total)
    if (tid < 200) {
        int row = tid % 50, seg = tid / 50;
        int c0 = seg * 75;
        const float* rp = cost + row * STRIDE + c0;
        float m = __builtin_inff(); int a = 0;
        for (int c = 0; c < 75; ++c) {
            float x = rp[c];
            if (x < m) { m = x; a = c0 + c; }   // strict < -> first occurrence
        }
        smin[seg*50 + row] = m;
        samin[seg*50 + row] = a;
    }
    __syncthreads();

    // ---- phase 2b: combine + greedy claim (wave0 lanes 0..49) ----
    float rm = __builtin_inff();
    int ram = 0;
    if (tid < NT) {
        rm = smin[tid]; ram = samin[tid];
        for (int s = 1; s < 4; ++s) {
            float ms = smin[s*50 + tid]; int as = samin[s*50 + tid];
            if (ms < rm || (ms == rm && as < ram)) { rm = ms; ram = as; }
        }
        atomicMin(&claim[ram], tid);   // greedy claim: smallest row wins
    }
    __syncthreads();
    if (wav != 0) return;              // no barriers below this point

    // ---- wave-0 distributed solver state ----
    double u_reg = (tid < NT) ? (double)rm : 0.0;  // lane t: u[t]
    int c4r = -1;                                  // lane t: col4row[t]
    if (tid < NT && claim[ram] == tid) c4r = ram;
    double v_reg[NSLOT];
    int r4c_reg[NSLOT];
#pragma unroll
    for (int k = 0; k < NSLOT; ++k) {
        int j = lane + (k << 6);
        v_reg[k] = 0.0;
        int cl = (j < NQ) ? claim[j] : 0x7fffffff;
        r4c_reg[k] = (cl != 0x7fffffff) ? cl : -1;
    }
    int att_cnt = 0;                               // lane t: requeues of row t
    u64_t arr = __ballot(tid < NT && c4r < 0);
    u64_t dij = 0;

    // ---- phase 3: JV augmenting row reduction (<= ARR_CAP requeues/row) ----
    while (arr) {
        int i = __builtin_ctzll(arr);
        arr &= arr - 1;
        const float* crow = cost + i * STRIDE;
        u64_t k1 = ~0ull;
        double v1 = __builtin_inf(), v2 = __builtin_inf();
#pragma unroll
        for (int k = 0; k < NSLOT; ++k) {
            int j = lane + (k << 6);
            if (j < NQ) {
                double m = (double)crow[j] - v_reg[k];
                u64_t kk = pack_key(m, j);
                if (kk < k1) { v2 = v1; v1 = m; k1 = kk; }
                else v2 = fmin(v2, m);
            }
        }
        // one joint DPP reduction: (argmin key, exact min1, exact min2)
        JSTEP(0x121, 0xf); JSTEP(0x122, 0xf); JSTEP(0x124, 0xf); JSTEP(0x128, 0xf);
        JSTEP(0x142, 0xa); JSTEP(0x143, 0xc);
        u64_t kmin = readlane_u64(k1, 63);
        double v1g = readlane_f64(v1, 63);         // exact min value
        double v2g = readlane_f64(v2, 63);         // exact second-min value
        int j1 = (int)(kmin & 511ull);
        int kj = j1 >> 6, lj = j1 & 63;
        int rsel; SEL5(rsel, r4c_reg, kj);
        int r = __builtin_amdgcn_readlane(rsel, lj);
        if (r < 0) {
            if (lane == lj) SET5(r4c_reg, kj, i);
            if (lane == i) { c4r = j1; u_reg = v1g; }
        } else {
            double cij = (double)crow[j1];         // uniform broadcast read
            if (lane == lj) { SET5(r4c_reg, kj, i); SET5(v_reg, kj, cij - v2g); }
            if (lane == i) { c4r = j1; u_reg = v2g; }
            if (lane == r) { c4r = -1; att_cnt++; }
            int ac = __builtin_amdgcn_readlane(att_cnt, r);
            u64_t rb = 1ull << r;
            if (ac <= ARR_CAP) arr |= rb; else dij |= rb;
        }
    }

    // ---- phase 4: Dijkstra (successive shortest paths) for leftovers ----
    while (dij) {
        int cur = __builtin_ctzll(dij);
        dij &= dij - 1;
        unsigned oncol = 0;
        u64_t onrow = 0;
        double short_reg[NSLOT];
        u64_t short_key[NSLOT];                  // +inf once column on tree
        int path_reg[NSLOT];
#pragma unroll
        for (int k = 0; k < NSLOT; ++k) {
            short_reg[k] = __builtin_inf(); short_key[k] = ~0ull; path_reg[k] = -1;
        }
        double min_val = 0.0;
        int i = cur, sink = -1;

        while (sink < 0) {
            onrow |= 1ull << i;
            double u_i = readlane_f64(u_reg, i);
            const float* crow = cost + i * STRIDE;
            u64_t bk = ~0ull;
#pragma unroll
            for (int k = 0; k < NSLOT; ++k) {
                int j = lane + (k << 6);
                if (j < NQ && !((oncol >> k) & 1u)) {
                    double d = ((min_val + (double)crow[j]) - u_i) - v_reg[k];
                    if (d < short_reg[k]) {
                        short_reg[k] = d; path_reg[k] = i;
                        short_key[k] = pack_key(d, j);
                    }
                }
                bk = minu64(bk, short_key[k]);
            }
            bk = wave_min_u64(bk);                 // uniform
            int j = (int)(bk & 511ull);
            int kj = j >> 6, lj = j & 63;
            double ssel; SEL5(ssel, short_reg, kj);
            min_val = readlane_f64(ssel, lj);      // exact winning value
            if (lane == lj) { oncol |= 1u << kj; SET5(short_key, kj, ~0ull); }
            int rsel; SEL5(rsel, r4c_reg, kj);
            int r = __builtin_amdgcn_readlane(rsel, lj);
            if (r < 0) sink = j; else i = r;
        }

        // dump shortest for the u-update gather (per-lane variable index)
#pragma unroll
        for (int k = 0; k < NSLOT; ++k) {
            int j = lane + (k << 6);
            if (j < NQ) sh_short[j] = short_reg[k];
        }
        wave_sync();
        double ss = (tid < NT && c4r >= 0) ? sh_short[c4r] : 0.0;
        if (tid < NT) {
            if (tid == cur) u_reg = u_reg + min_val;
            else if ((onrow >> tid) & 1ull) u_reg = u_reg + (min_val - ss);
        }
#pragma unroll
        for (int k = 0; k < NSLOT; ++k) {
            int j = lane + (k << 6);
            if (j < NQ && ((oncol >> k) & 1u))
                v_reg[k] = v_reg[k] - (min_val - short_reg[k]);
        }

        // augmentation walk: registers + readlane only
        int jj = sink;
        while (true) {
            int kk2 = jj >> 6, ll = jj & 63;
            int psel; SEL5(psel, path_reg, kk2);
            int ii = __builtin_amdgcn_readlane(psel, ll);
            if (lane == ll) SET5(r4c_reg, kk2, ii);
            int nj = __builtin_amdgcn_readlane(c4r, ii);  // old col4row[ii]
            if (lane == ii) c4r = jj;
            jj = nj;
            if (ii == cur) break;
        }
    }

    // ---- output: pairs (pred=col4row[t], truth=t) sorted by pred index ----
    if (tid < NT) sh_c4r[tid] = c4r;
    wave_sync();
    if (tid < NT) {
        int it = c4r;
        int rank = 0;
        for (int t2 = 0; t2 < NT; ++t2) rank += (sh_c4r[t2] < it) ? 1 : 0;
        out[b * 2 * NT + rank] = it;             // row 0: sorted pred indices
        out[b * 2 * NT + NT + rank] = tid;       // row 1: matching truth indices
    }
}

extern "C" void kernel_launch(void* const* d_in, const int* in_sizes, int n_in,
                              void* d_out, int out_size, void* d_ws, size_t ws_size,
                              hipStream_t stream) {
    const float* pred  = (const float*)d_in[0];   // (32, 300, 4) f32
    const float* truth = (const float*)d_in[1];   // (32, 50, 4)  f32
    int* out = (int*)d_out;                       // (32, 2, 50)  int32
    hungarian_kernel<<<32, NTHREADS, 0, stream>>>(pred, truth, out);
}